// Round 5
// baseline (395.489 us; speedup 1.0000x reference)
//
#include <hip/hip_runtime.h>
#include <math.h>

#define LN      2048
#define LOG2L   11
#define BB      16
#define HE      512            // H*E channels
#define KTOP    7              // int(log(2048)) = 7
#define TWO_PI  6.283185307179586f
#define RC      0.70710678118654752f

// XOR swizzle on element index (float2 elems) for LDS FFT buffers (fallback).
#define SIG(e)  ((e) ^ (((e) >> 5) & 31))

struct c32 { float x, y; };
__device__ __forceinline__ c32 cmul(c32 a, c32 b) {
    return { a.x * b.x - a.y * b.y, a.x * b.y + a.y * b.x };
}
__device__ __forceinline__ c32 cadd(c32 a, c32 b) { return { a.x + b.x, a.y + b.y }; }
__device__ __forceinline__ c32 csub(c32 a, c32 b) { return { a.x - b.x, a.y - b.y }; }

__device__ __forceinline__ void dft4(c32 a, c32 b, c32 c, c32 d,
                                     c32& y0, c32& y1, c32& y2, c32& y3) {
    c32 t0 = cadd(a, c), t1 = csub(a, c);
    c32 t2 = cadd(b, d);
    c32 t3 = { b.y - d.y, d.x - b.x };          // -i*(b-d)
    y0 = cadd(t0, t2);
    y1 = cadd(t1, t3);
    y2 = csub(t0, t2);
    y3 = csub(t1, t3);
}

__device__ __forceinline__ void dft8(const c32* x, c32* y) {
    c32 e0, e1, e2, e3, o0, o1, o2, o3;
    dft4(x[0], x[2], x[4], x[6], e0, e1, e2, e3);
    dft4(x[1], x[3], x[5], x[7], o0, o1, o2, o3);
    c32 p1 = { RC * (o1.x + o1.y), RC * (o1.y - o1.x) };
    c32 p2 = { o2.y, -o2.x };
    c32 p3 = { RC * (o3.y - o3.x), -RC * (o3.x + o3.y) };
    y[0] = cadd(e0, o0); y[4] = csub(e0, o0);
    y[1] = cadd(e1, p1); y[5] = csub(e1, p1);
    y[2] = cadd(e2, p2); y[6] = csub(e2, p2);
    y[3] = cadd(e3, p3); y[7] = csub(e3, p3);
}

// W_32^t = (cos(2pi t/32), -sin(2pi t/32)), t in [0,22)
__device__ __forceinline__ c32 W32f(int t) {
    constexpr float C[22] = { 1.f, 0.98078528f, 0.92387953f, 0.83146961f,
        0.70710678f, 0.55557023f, 0.38268343f, 0.19509032f, 0.f, -0.19509032f,
        -0.38268343f, -0.55557023f, -0.70710678f, -0.83146961f, -0.92387953f,
        -0.98078528f, -1.f, -0.98078528f, -0.92387953f, -0.83146961f,
        -0.70710678f, -0.55557023f };
    constexpr float S[22] = { 0.f, 0.19509032f, 0.38268343f, 0.55557023f,
        0.70710678f, 0.83146961f, 0.92387953f, 0.98078528f, 1.f, 0.98078528f,
        0.92387953f, 0.83146961f, 0.70710678f, 0.55557023f, 0.38268343f,
        0.19509032f, 0.f, -0.19509032f, -0.38268343f, -0.55557023f, -0.70710678f,
        -0.83146961f };
    return { C[t], -S[t] };
}

// 32-pt DFT in registers, natural in/out. 32 = 8(m1) x 4(m2), n1 = 4*m1+m2.
__device__ __forceinline__ void dft32(const c32* x, c32* y) {
    c32 A[4][8];
    #pragma unroll
    for (int m2 = 0; m2 < 4; ++m2) {
        c32 in[8];
        #pragma unroll
        for (int m1 = 0; m1 < 8; ++m1) in[m1] = x[(m1 << 2) | m2];
        dft8(in, A[m2]);
    }
    #pragma unroll
    for (int k1 = 0; k1 < 8; ++k1) {
        c32 t0 = A[0][k1];
        c32 t1 = cmul(A[1][k1], W32f(k1));
        c32 t2 = cmul(A[2][k1], W32f(2 * k1));
        c32 t3 = cmul(A[3][k1], W32f(3 * k1));
        c32 y0, y1, y2, y3;
        dft4(t0, t1, t2, t3, y0, y1, y2, y3);
        y[k1] = y0; y[k1 + 8] = y1; y[k1 + 16] = y2; y[k1 + 24] = y3;
    }
}

__device__ __forceinline__ c32 shflx(c32 v, int m) {
    return { __shfl_xor(v.x, m, 64), __shfl_xor(v.y, m, 64) };
}
__device__ __forceinline__ c32 shfli(c32 v, int s) {
    return { __shfl(v.x, s, 64), __shfl(v.y, s, 64) };
}

__device__ __forceinline__ void unp_acc(float* sxl, float* syl, int idx,
                                        c32 zf, c32 zm) {
    const float Qr = 0.5f * (zf.x + zm.x);
    const float Qi = 0.5f * (zf.y - zm.y);
    const float Kr = 0.5f * (zf.y + zm.y);
    const float Ki = -0.5f * (zf.x - zm.x);
    atomicAdd(&sxl[idx], Qr * Kr + Qi * Ki);
    atomicAdd(&syl[idx], Qi * Kr - Qr * Ki);
}

// ---------------------------------------------------------------------------
// Kernel T: coalesced transpose+split. q,k [b][l][c] -> qT,kT [b][c][l].
// ---------------------------------------------------------------------------
__global__ __launch_bounds__(256) void transpose_pack_kernel(
    const float* __restrict__ q, const float* __restrict__ k,
    float* __restrict__ qT, float* __restrict__ kT) {
    __shared__ float2 tile[64][65];
    const int tid = threadIdx.x;
    const int bid = blockIdx.x;
    const int b  = bid >> 8;
    const int lt = (bid >> 3) & 31;
    const int ct = bid & 7;
    const int l0 = lt << 6, c0 = ct << 6;
    const int col = tid & 63, row = tid >> 6;
    #pragma unroll
    for (int rr = 0; rr < 16; ++rr) {
        const int r = (rr << 2) + row;
        const size_t src = ((size_t)(b * LN + l0 + r)) * HE + c0 + col;
        tile[r][col] = make_float2(q[src], k[src]);
    }
    __syncthreads();
    #pragma unroll
    for (int rr = 0; rr < 16; ++rr) {
        const int r = (rr << 2) + row;
        const float2 v = tile[col][r];
        const size_t dst = ((size_t)(b * HE + c0 + r)) * LN + l0 + col;
        qT[dst] = v.x;
        kT[dst] = v.y;
    }
}

// ---------------------------------------------------------------------------
// Kernel A: barrier-free two-step shuffle FFT. 2048 = 32(regs) x 64(lanes).
// One wave per 4 channels: per-lane DFT32 -> twiddle -> 6 shfl_xor DIF
// stages -> unpack S=Q*conj(K) via shfl_xor(63) pairing -> LDS ds-atomic
// accumulate over the WG's 16 channels -> one global-atomic flush per WG.
// ---------------------------------------------------------------------------
__global__ __launch_bounds__(256) void fft_shfl_kernel(
    const float* __restrict__ qT, const float* __restrict__ kT,
    float* __restrict__ spec /* [BB][LN][2] */) {
    __shared__ float sxl[LN];
    __shared__ float syl[LN];
    const int tid  = threadIdx.x;
    const int lane = tid & 63;
    const int wv   = tid >> 6;
    const int W    = (blockIdx.x << 2) | wv;       // global wave id, 2048
    const int b    = W >> 7;
    const int cb   = (W & 127) << 2;
    const int rv   = __brev(lane) >> 26;           // bitrev6(lane)

    for (int i = tid; i < LN; i += 256) { sxl[i] = 0.f; syl[i] = 0.f; }
    __syncthreads();

    // per-lane constants (channel-independent)
    c32 wb[8];                                     // W_2048^{lane*j}
    #pragma unroll
    for (int j = 0; j < 8; ++j) {
        float sn, cs;
        __sincosf(-(TWO_PI / (float)LN) * (float)(lane * j), &sn, &cs);
        wb[j] = { cs, sn };
    }
    c32 w8l;                                       // W_2048^{8*lane}
    {
        float sn, cs;
        __sincosf(-(TWO_PI / (float)LN) * (float)(lane << 3), &sn, &cs);
        w8l = { cs, sn };
    }
    c32 wst[5];                                    // stage twiddles W_64^e
    #pragma unroll
    for (int si = 0; si < 5; ++si) {
        const int d = 32 >> si;
        const int e = (lane & (d - 1)) << si;
        float sn, cs;
        __sincosf(-(TWO_PI / 64.f) * (float)e, &sn, &cs);
        wst[si] = { cs, sn };
    }
    const int l0src = __brev((64 - rv) & 63) >> 26;  // partner lane for reg 0

    #pragma unroll 1
    for (int ch = 0; ch < 4; ++ch) {
        const size_t base = ((size_t)(b * HE + cb + ch)) << LOG2L;
        // load z[n1] = q[64*n1+lane] + i*k[64*n1+lane]  (coalesced 256B/instr)
        c32 x[32];
        #pragma unroll
        for (int n1 = 0; n1 < 32; ++n1) {
            x[n1].x = qT[base + (n1 << 6) + lane];
            x[n1].y = kT[base + (n1 << 6) + lane];
        }
        // step 1: DFT32 over registers
        c32 z[32];
        dft32(x, z);
        // step 2: twiddle z[k1] *= W_2048^{lane*k1}
        c32 acc = { 1.f, 0.f };
        #pragma unroll
        for (int a = 0; a < 4; ++a) {
            #pragma unroll
            for (int j = 0; j < 8; ++j) {
                z[(a << 3) | j] = cmul(z[(a << 3) | j], cmul(acc, wb[j]));
            }
            acc = cmul(acc, w8l);
        }
        // step 3: DFT64 across lanes, DIF radix-2, 6 stages.
        // After this, lane holds X[k1 + 32*rv] in z[k1].
        #pragma unroll
        for (int si = 0; si < 6; ++si) {
            const int d = 32 >> si;
            const bool hi = (lane & d) != 0;
            #pragma unroll
            for (int k1 = 0; k1 < 32; ++k1) {
                c32 p  = shflx(z[k1], d);
                c32 lo = cadd(z[k1], p);
                c32 hv = csub(p, z[k1]);
                if (si < 5) hv = cmul(hv, wst[si]);
                z[k1] = hi ? hv : lo;
            }
        }
        // step 4: unpack S = Q*conj(K); partner of f=k1+32*k2 is reg 32-k1
        // at lane^63 (k1>0); reg 0 partner via bpermute.
        {
            c32 m0 = shfli(z[0], l0src);
            unp_acc(sxl, syl, (0 << 6) | rv, z[0], m0);
            c32 m16 = shflx(z[16], 63);
            unp_acc(sxl, syl, (16 << 6) | rv, z[16], m16);
            #pragma unroll
            for (int k1 = 1; k1 < 16; ++k1) {
                c32 ma = shflx(z[32 - k1], 63);
                c32 mb = shflx(z[k1], 63);
                unp_acc(sxl, syl, (k1 << 6) | rv, z[k1], ma);
                unp_acc(sxl, syl, ((32 - k1) << 6) | rv, z[32 - k1], mb);
            }
        }
    }
    __syncthreads();
    // flush: idx i = (k1<<6)|rv  ->  f = k1 + 32*rv
    for (int i = tid; i < LN; i += 256) {
        const int f = (i >> 6) | ((i & 63) << 5);
        atomicAdd(&spec[((size_t)b * LN + f) * 2 + 0], sxl[i]);
        atomicAdd(&spec[((size_t)b * LN + f) * 2 + 1], syl[i]);
    }
}

// ---------------------------------------------------------------------------
// Fallback helpers + kernel (round-3 fused, reads raw layout; used only
// when ws is too small for the transposed staging buffer).
// ---------------------------------------------------------------------------
template<int LOG2M>
__device__ __forceinline__ void r8_stage(float2* Z, int lane) {
    c32 v[32];
    #pragma unroll
    for (int u = 0; u < 4; ++u) {
        const int j = lane + (u << 6);
        #pragma unroll
        for (int r = 0; r < 8; ++r) {
            float2 z = Z[SIG(j + (r << 8))];
            v[(u << 3) + r] = { z.x, z.y };
        }
    }
    c32 y[32];
    #pragma unroll
    for (int u = 0; u < 4; ++u) {
        const int j  = lane + (u << 6);
        const int pm = j & ~((1 << LOG2M) - 1);
        dft8(&v[u << 3], &y[u << 3]);
        float sn, cs;
        __sincosf(-(TWO_PI / (float)LN) * (float)pm, &sn, &cs);
        c32 base = { cs, sn };
        c32 t = base;
        #pragma unroll
        for (int kk = 1; kk < 8; ++kk) {
            y[(u << 3) + kk] = cmul(y[(u << 3) + kk], t);
            if (kk < 7) t = cmul(t, base);
        }
    }
    __syncthreads();
    #pragma unroll
    for (int u = 0; u < 4; ++u) {
        const int j  = lane + (u << 6);
        const int q_ = j & ((1 << LOG2M) - 1);
        const int ob = q_ + ((j - q_) << 3);
        #pragma unroll
        for (int kk = 0; kk < 8; ++kk) {
            c32 yy = y[(u << 3) + kk];
            Z[SIG(ob + (kk << LOG2M))] = make_float2(yy.x, yy.y);
        }
    }
    __syncthreads();
}

__device__ __forceinline__ void r4_final(float2* Z, int lane) {
    c32 v[32];
    #pragma unroll
    for (int u = 0; u < 8; ++u) {
        const int j = lane + (u << 6);
        #pragma unroll
        for (int r = 0; r < 4; ++r) {
            float2 z = Z[SIG(j + (r << 9))];
            v[(u << 2) + r] = { z.x, z.y };
        }
    }
    __syncthreads();
    #pragma unroll
    for (int u = 0; u < 8; ++u) {
        const int j = lane + (u << 6);
        c32 y0, y1, y2, y3;
        dft4(v[u << 2], v[(u << 2) + 1], v[(u << 2) + 2], v[(u << 2) + 3],
             y0, y1, y2, y3);
        Z[SIG(j)]        = make_float2(y0.x, y0.y);
        Z[SIG(j + 512)]  = make_float2(y1.x, y1.y);
        Z[SIG(j + 1024)] = make_float2(y2.x, y2.y);
        Z[SIG(j + 1536)] = make_float2(y3.x, y3.y);
    }
    __syncthreads();
}

__global__ __launch_bounds__(256) void fft_fused_kernel(
    const float* __restrict__ qg, const float* __restrict__ kg,
    float* __restrict__ spec) {
    __shared__ float2 zb[4][LN];
    const int t    = threadIdx.x;
    const int bid  = blockIdx.x;
    const int wgid = ((bid & 7) << 8) | (bid >> 3);
    const int b    = wgid >> 7;
    const int c0   = (wgid & 127) << 2;
    #pragma unroll
    for (int i = 0; i < 8; ++i) {
        const int l = t + (i << 8);
        const size_t base = (size_t)(b * LN + l) * HE + c0;
        const float4 qv = *(const float4*)(qg + base);
        const float4 kv = *(const float4*)(kg + base);
        const int sl = SIG(l);
        zb[0][sl] = make_float2(qv.x, kv.x);
        zb[1][sl] = make_float2(qv.y, kv.y);
        zb[2][sl] = make_float2(qv.z, kv.z);
        zb[3][sl] = make_float2(qv.w, kv.w);
    }
    __syncthreads();
    const int w    = t >> 6;
    const int lane = t & 63;
    float2* Z = zb[w];
    r8_stage<0>(Z, lane);
    r8_stage<3>(Z, lane);
    r8_stage<6>(Z, lane);
    r4_final(Z, lane);
    float sx[32], sy[32];
    #pragma unroll
    for (int i = 0; i < 32; ++i) {
        const int f = lane + (i << 6);
        const float2 zf = Z[SIG(f)];
        const float2 zm = Z[SIG((LN - f) & (LN - 1))];
        const float Qr = 0.5f * (zf.x + zm.x);
        const float Qi = 0.5f * (zf.y - zm.y);
        const float Kr = 0.5f * (zf.y + zm.y);
        const float Ki = -0.5f * (zf.x - zm.x);
        sx[i] = Qr * Kr + Qi * Ki;
        sy[i] = Qi * Kr - Qr * Ki;
    }
    __syncthreads();
    #pragma unroll
    for (int i = 0; i < 32; ++i) {
        const int f = lane + (i << 6);
        Z[SIG(f)] = make_float2(sx[i], sy[i]);
    }
    __syncthreads();
    #pragma unroll
    for (int i = 0; i < 8; ++i) {
        const int f  = t + (i << 8);
        const int sf = SIG(f);
        const float rx = zb[0][sf].x + zb[1][sf].x + zb[2][sf].x + zb[3][sf].x;
        const float ry = zb[0][sf].y + zb[1][sf].y + zb[2][sf].y + zb[3][sf].y;
        atomicAdd(&spec[((size_t)b * LN + f) * 2 + 0], rx);
        atomicAdd(&spec[((size_t)b * LN + f) * 2 + 1], ry);
    }
}

// ---------------------------------------------------------------------------
// Kernel B: per-b inverse transform -> mean corr, top-7 + softmax.
// ---------------------------------------------------------------------------
__device__ __forceinline__ unsigned bitrev11(unsigned x) {
    return __brev(x) >> (32 - LOG2L);
}

__global__ __launch_bounds__(256) void icorr_topk_kernel(
    const float* __restrict__ spec, float* __restrict__ wts, int* __restrict__ tao) {
    __shared__ float2 zbuf[LN];
    __shared__ float2 tw[LN / 2];
    __shared__ float  cr[LN];
    __shared__ float  rv[256];
    __shared__ int    ri[256];
    __shared__ float  topv[KTOP];
    __shared__ int    topi[KTOP];
    const int tid = threadIdx.x;
    const int b   = blockIdx.x;
    for (int p = tid; p < LN / 2; p += 256) {
        float s, c;
        sincosf(-TWO_PI * (float)p / (float)LN, &s, &c);
        tw[p] = make_float2(c, s);
    }
    for (int f = tid; f < LN; f += 256) {
        float sr = spec[((size_t)b * LN + f) * 2 + 0];
        float si = spec[((size_t)b * LN + f) * 2 + 1];
        zbuf[bitrev11((unsigned)f)] = make_float2(sr, -si);
    }
    __syncthreads();
    for (int s = 0; s < LOG2L; ++s) {
        const int half = 1 << s;
        for (int j = tid; j < LN / 2; j += 256) {
            const int grp = j >> s;
            const int pos = j & (half - 1);
            const int i0  = (grp << (s + 1)) + pos;
            const int i1  = i0 + half;
            const float2 w = tw[pos << (LOG2L - 1 - s)];
            float2 a  = zbuf[i0];
            float2 bv = zbuf[i1];
            float tr = w.x * bv.x - w.y * bv.y;
            float ti = w.x * bv.y + w.y * bv.x;
            zbuf[i0] = make_float2(a.x + tr, a.y + ti);
            zbuf[i1] = make_float2(a.x - tr, a.y - ti);
        }
        __syncthreads();
    }
    const float scale = 1.0f / ((float)LN * (float)HE);
    for (int t = tid; t < LN; t += 256) cr[t] = zbuf[t].x * scale;
    __syncthreads();
    for (int it = 0; it < KTOP; ++it) {
        float mv = -INFINITY;
        int   mi = 0;
        for (int t = tid; t < LN; t += 256) {
            float v = cr[t];
            if (v > mv) { mv = v; mi = t; }
        }
        rv[tid] = mv; ri[tid] = mi;
        __syncthreads();
        for (int off = 128; off > 0; off >>= 1) {
            if (tid < off) {
                float ov = rv[tid + off]; int oi = ri[tid + off];
                if (ov > rv[tid] || (ov == rv[tid] && oi < ri[tid])) {
                    rv[tid] = ov; ri[tid] = oi;
                }
            }
            __syncthreads();
        }
        if (tid == 0) {
            topv[it] = rv[0];
            topi[it] = ri[0];
            cr[ri[0]] = -INFINITY;
        }
        __syncthreads();
    }
    if (tid == 0) {
        float m = topv[0];
        float s = 0.f;
        float ex[KTOP];
        for (int j = 0; j < KTOP; ++j) { ex[j] = __expf(topv[j] - m); s += ex[j]; }
        float inv = 1.0f / s;
        for (int j = 0; j < KTOP; ++j) {
            wts[b * 8 + j] = ex[j] * inv;
            tao[b * 8 + j] = topi[j];
        }
    }
}

// ---------------------------------------------------------------------------
// Kernel C: out[b,l,:,:] = sum_j w[b,j] * V[b,(l+tao_j)%L,:,:]
// ---------------------------------------------------------------------------
__global__ __launch_bounds__(256) void gather_kernel(
    const float* __restrict__ v, const float* __restrict__ wts,
    const int* __restrict__ tao, float* __restrict__ out) {
    __shared__ float lw[KTOP];
    __shared__ int   lt[KTOP];
    const int tid = threadIdx.x;
    const int bid = blockIdx.x;
    const int wg  = ((bid & 7) << 11) | (bid >> 3);
    const long long idx = (long long)wg * 256 + tid;
    const int c4 = (int)(idx & 127);
    const int l  = (int)((idx >> 7) & (LN - 1));
    const int b  = (int)(idx >> 18);
    if (tid < KTOP) {
        lw[tid] = wts[b * 8 + tid];
        lt[tid] = tao[b * 8 + tid];
    }
    __syncthreads();
    const float4* v4 = (const float4*)v;
    float4 a = make_float4(0.f, 0.f, 0.f, 0.f);
    #pragma unroll
    for (int j = 0; j < KTOP; ++j) {
        int ls = (l + lt[j]) & (LN - 1);
        float4 x = v4[((size_t)b * LN + ls) * 128 + c4];
        float w = lw[j];
        a.x += w * x.x; a.y += w * x.y; a.z += w * x.z; a.w += w * x.w;
    }
    ((float4*)out)[idx] = a;
}

// ---------------------------------------------------------------------------
extern "C" void kernel_launch(void* const* d_in, const int* in_sizes, int n_in,
                              void* d_out, int out_size, void* d_ws, size_t ws_size,
                              hipStream_t stream) {
    const float* q = (const float*)d_in[0];
    const float* k = (const float*)d_in[1];
    const float* v = (const float*)d_in[2];
    float* out = (float*)d_out;

    const size_t nT   = (size_t)BB * HE * LN;          // 64 MB of floats
    const size_t need = nT * 4 + (size_t)BB * LN * 2 * 4 + (size_t)BB * 8 * 8;

    if (ws_size >= need) {
        float* kT   = (float*)d_ws;
        float* spec = kT + nT;
        float* wts  = spec + (size_t)BB * LN * 2;
        int*   tao  = (int*)(wts + BB * 8);
        float* qT   = out;   // staged in d_out, overwritten by gather later

        hipMemsetAsync(spec, 0, (size_t)BB * LN * 2 * sizeof(float), stream);
        transpose_pack_kernel<<<BB * 32 * 8, 256, 0, stream>>>(q, k, qT, kT);
        fft_shfl_kernel<<<512, 256, 0, stream>>>(qT, kT, spec);
        icorr_topk_kernel<<<BB, 256, 0, stream>>>(spec, wts, tao);
        const int n4 = BB * LN * HE / 4;
        gather_kernel<<<n4 / 256, 256, 0, stream>>>(v, wts, tao, out);
    } else {
        float* spec = (float*)d_ws;
        float* wts  = spec + (size_t)BB * LN * 2;
        int*   tao  = (int*)(wts + BB * 8);
        hipMemsetAsync(spec, 0, (size_t)BB * LN * 2 * sizeof(float), stream);
        fft_fused_kernel<<<BB * (HE / 4), 256, 0, stream>>>(q, k, spec);
        icorr_topk_kernel<<<BB, 256, 0, stream>>>(spec, wts, tao);
        const int n4 = BB * LN * HE / 4;
        gather_kernel<<<n4 / 256, 256, 0, stream>>>(v, wts, tao, out);
    }
}

// Round 6
// 175.154 us; speedup vs baseline: 2.2580x; 2.2580x over previous
//
#include <hip/hip_runtime.h>
#include <math.h>

#define LN      2048
#define LOG2L   11
#define BB      16
#define HE      512            // H*E channels
#define KTOP    7              // int(log(2048)) = 7
#define TWO_PI  6.283185307179586f
#define RC      0.70710678118654752f

// XOR swizzle on element index (float2 elems) for LDS FFT buffers.
#define SIG(e)  ((e) ^ (((e) >> 5) & 31))

struct c32 { float x, y; };
__device__ __forceinline__ c32 cmul(c32 a, c32 b) {
    return { a.x * b.x - a.y * b.y, a.x * b.y + a.y * b.x };
}
__device__ __forceinline__ c32 cadd(c32 a, c32 b) { return { a.x + b.x, a.y + b.y }; }
__device__ __forceinline__ c32 csub(c32 a, c32 b) { return { a.x - b.x, a.y - b.y }; }

__device__ __forceinline__ void dft4(c32 a, c32 b, c32 c, c32 d,
                                     c32& y0, c32& y1, c32& y2, c32& y3) {
    c32 t0 = cadd(a, c), t1 = csub(a, c);
    c32 t2 = cadd(b, d);
    c32 t3 = { b.y - d.y, d.x - b.x };          // -i*(b-d)
    y0 = cadd(t0, t2);
    y1 = cadd(t1, t3);
    y2 = csub(t0, t2);
    y3 = csub(t1, t3);
}

__device__ __forceinline__ void dft8(const c32* x, c32* y) {
    c32 e0, e1, e2, e3, o0, o1, o2, o3;
    dft4(x[0], x[2], x[4], x[6], e0, e1, e2, e3);
    dft4(x[1], x[3], x[5], x[7], o0, o1, o2, o3);
    c32 p1 = { RC * (o1.x + o1.y), RC * (o1.y - o1.x) };
    c32 p2 = { o2.y, -o2.x };
    c32 p3 = { RC * (o3.y - o3.x), -RC * (o3.x + o3.y) };
    y[0] = cadd(e0, o0); y[4] = csub(e0, o0);
    y[1] = cadd(e1, p1); y[5] = csub(e1, p1);
    y[2] = cadd(e2, p2); y[6] = csub(e2, p2);
    y[3] = cadd(e3, p3); y[7] = csub(e3, p3);
}

// One Stockham DIF radix-8 stage over a 2048-pt buffer, 256 threads:
// exactly one butterfly per thread. In-place (SIG swizzle), 2 barriers.
template<int LOG2M>
__device__ __forceinline__ void r8_stage_wg(float2* Z, int tid) {
    c32 v[8];
    const int j = tid;                           // 256 butterflies
    #pragma unroll
    for (int r = 0; r < 8; ++r) {
        float2 z = Z[SIG(j + (r << 8))];
        v[r] = { z.x, z.y };
    }
    c32 y[8];
    dft8(v, y);
    const int pm = j & ~((1 << LOG2M) - 1);      // m*p
    float sn, cs;
    __sincosf(-(TWO_PI / (float)LN) * (float)pm, &sn, &cs);
    c32 base = { cs, sn };
    c32 t = base;
    #pragma unroll
    for (int kk = 1; kk < 8; ++kk) {
        y[kk] = cmul(y[kk], t);
        if (kk < 7) t = cmul(t, base);
    }
    __syncthreads();
    const int q_ = j & ((1 << LOG2M) - 1);
    const int ob = q_ + ((j - q_) << 3);         // q + 8*m*p
    #pragma unroll
    for (int kk = 0; kk < 8; ++kk) {
        Z[SIG(ob + (kk << LOG2M))] = make_float2(y[kk].x, y[kk].y);
    }
    __syncthreads();
}

// Final radix-4 stage, m=512 (twiddle-free), 512 butterflies / 256 threads.
__device__ __forceinline__ void r4_final_wg(float2* Z, int tid) {
    c32 v[2][4];
    #pragma unroll
    for (int u = 0; u < 2; ++u) {
        const int j = tid + (u << 8);
        #pragma unroll
        for (int r = 0; r < 4; ++r) {
            float2 z = Z[SIG(j + (r << 9))];
            v[u][r] = { z.x, z.y };
        }
    }
    __syncthreads();
    #pragma unroll
    for (int u = 0; u < 2; ++u) {
        const int j = tid + (u << 8);
        c32 y0, y1, y2, y3;
        dft4(v[u][0], v[u][1], v[u][2], v[u][3], y0, y1, y2, y3);
        Z[SIG(j)]        = make_float2(y0.x, y0.y);
        Z[SIG(j + 512)]  = make_float2(y1.x, y1.y);
        Z[SIG(j + 1024)] = make_float2(y2.x, y2.y);
        Z[SIG(j + 1536)] = make_float2(y3.x, y3.y);
    }
    __syncthreads();
}

// ---------------------------------------------------------------------------
// Kernel T: coalesced transpose+split. q,k [b][l][c] -> qT,kT [b][c][l].
// ---------------------------------------------------------------------------
__global__ __launch_bounds__(256) void transpose_pack_kernel(
    const float* __restrict__ q, const float* __restrict__ k,
    float* __restrict__ qT, float* __restrict__ kT) {
    __shared__ float2 tile[64][65];
    const int tid = threadIdx.x;
    const int bid = blockIdx.x;
    const int b  = bid >> 8;
    const int lt = (bid >> 3) & 31;
    const int ct = bid & 7;
    const int l0 = lt << 6, c0 = ct << 6;
    const int col = tid & 63, row = tid >> 6;
    #pragma unroll
    for (int rr = 0; rr < 16; ++rr) {
        const int r = (rr << 2) + row;
        const size_t src = ((size_t)(b * LN + l0 + r)) * HE + c0 + col;
        tile[r][col] = make_float2(q[src], k[src]);
    }
    __syncthreads();
    #pragma unroll
    for (int rr = 0; rr < 16; ++rr) {
        const int r = (rr << 2) + row;
        const float2 v = tile[col][r];
        const size_t dst = ((size_t)(b * HE + c0 + r)) * LN + l0 + col;
        qT[dst] = v.x;
        kT[dst] = v.y;
    }
}

// ---------------------------------------------------------------------------
// Kernel A: whole-WG-per-channel in-place register/LDS FFT (radix 8/8/8/4)
// over one 16 KB buffer. 4 channels sequential per WG; S=Q*conj(K)
// accumulated in registers; one atomic flush per WG. 10 barriers/channel.
// ---------------------------------------------------------------------------
__global__ __launch_bounds__(256) void fft_wg_kernel(
    const float* __restrict__ qT, const float* __restrict__ kT,
    float* __restrict__ spec /* [BB][LN][2] */) {
    __shared__ float2 Z[LN];                     // 16 KB
    const int tid = threadIdx.x;
    const int wg  = blockIdx.x;                  // 2048
    const int b   = wg >> 7;
    const int c0  = (wg & 127) << 2;

    float accx[8], accy[8];
    #pragma unroll
    for (int i = 0; i < 8; ++i) { accx[i] = 0.f; accy[i] = 0.f; }

    #pragma unroll 1
    for (int ch = 0; ch < 4; ++ch) {
        const size_t base = ((size_t)(b * HE + c0 + ch)) << LOG2L;
        const float4* q4 = (const float4*)(qT + base);
        const float4* k4 = (const float4*)(kT + base);
        #pragma unroll
        for (int i = 0; i < 2; ++i) {
            const int i4 = tid + (i << 8);       // float4 idx 0..511
            const float4 qv = q4[i4];
            const float4 kv = k4[i4];
            const int l = i4 << 2;
            Z[SIG(l)]     = make_float2(qv.x, kv.x);
            Z[SIG(l + 1)] = make_float2(qv.y, kv.y);
            Z[SIG(l + 2)] = make_float2(qv.z, kv.z);
            Z[SIG(l + 3)] = make_float2(qv.w, kv.w);
        }
        __syncthreads();

        r8_stage_wg<0>(Z, tid);
        r8_stage_wg<3>(Z, tid);
        r8_stage_wg<6>(Z, tid);
        r4_final_wg(Z, tid);

        // unpack packed transform: S = Q*conj(K); accumulate in registers
        #pragma unroll
        for (int i = 0; i < 8; ++i) {
            const int f = tid + (i << 8);
            const float2 zf = Z[SIG(f)];
            const float2 zm = Z[SIG((LN - f) & (LN - 1))];
            const float Qr = 0.5f * (zf.x + zm.x);
            const float Qi = 0.5f * (zf.y - zm.y);
            const float Kr = 0.5f * (zf.y + zm.y);
            const float Ki = -0.5f * (zf.x - zm.x);
            accx[i] += Qr * Kr + Qi * Ki;
            accy[i] += Qi * Kr - Qr * Ki;
        }
        __syncthreads();                         // before next channel's load
    }
    #pragma unroll
    for (int i = 0; i < 8; ++i) {
        const int f = tid + (i << 8);
        atomicAdd(&spec[((size_t)b * LN + f) * 2 + 0], accx[i]);
        atomicAdd(&spec[((size_t)b * LN + f) * 2 + 1], accy[i]);
    }
}

// ---------------------------------------------------------------------------
// Fallback (raw layout, round-3 path) — only if ws too small.
// ---------------------------------------------------------------------------
template<int LOG2M>
__device__ __forceinline__ void r8_stage(float2* Z, int lane) {
    c32 v[32];
    #pragma unroll
    for (int u = 0; u < 4; ++u) {
        const int j = lane + (u << 6);
        #pragma unroll
        for (int r = 0; r < 8; ++r) {
            float2 z = Z[SIG(j + (r << 8))];
            v[(u << 3) + r] = { z.x, z.y };
        }
    }
    c32 y[32];
    #pragma unroll
    for (int u = 0; u < 4; ++u) {
        const int j  = lane + (u << 6);
        const int pm = j & ~((1 << LOG2M) - 1);
        dft8(&v[u << 3], &y[u << 3]);
        float sn, cs;
        __sincosf(-(TWO_PI / (float)LN) * (float)pm, &sn, &cs);
        c32 base = { cs, sn };
        c32 t = base;
        #pragma unroll
        for (int kk = 1; kk < 8; ++kk) {
            y[(u << 3) + kk] = cmul(y[(u << 3) + kk], t);
            if (kk < 7) t = cmul(t, base);
        }
    }
    __syncthreads();
    #pragma unroll
    for (int u = 0; u < 4; ++u) {
        const int j  = lane + (u << 6);
        const int q_ = j & ((1 << LOG2M) - 1);
        const int ob = q_ + ((j - q_) << 3);
        #pragma unroll
        for (int kk = 0; kk < 8; ++kk) {
            c32 yy = y[(u << 3) + kk];
            Z[SIG(ob + (kk << LOG2M))] = make_float2(yy.x, yy.y);
        }
    }
    __syncthreads();
}

__device__ __forceinline__ void r4_final(float2* Z, int lane) {
    c32 v[32];
    #pragma unroll
    for (int u = 0; u < 8; ++u) {
        const int j = lane + (u << 6);
        #pragma unroll
        for (int r = 0; r < 4; ++r) {
            float2 z = Z[SIG(j + (r << 9))];
            v[(u << 2) + r] = { z.x, z.y };
        }
    }
    __syncthreads();
    #pragma unroll
    for (int u = 0; u < 8; ++u) {
        const int j = lane + (u << 6);
        c32 y0, y1, y2, y3;
        dft4(v[u << 2], v[(u << 2) + 1], v[(u << 2) + 2], v[(u << 2) + 3],
             y0, y1, y2, y3);
        Z[SIG(j)]        = make_float2(y0.x, y0.y);
        Z[SIG(j + 512)]  = make_float2(y1.x, y1.y);
        Z[SIG(j + 1024)] = make_float2(y2.x, y2.y);
        Z[SIG(j + 1536)] = make_float2(y3.x, y3.y);
    }
    __syncthreads();
}

__global__ __launch_bounds__(256) void fft_fused_kernel(
    const float* __restrict__ qg, const float* __restrict__ kg,
    float* __restrict__ spec) {
    __shared__ float2 zb[4][LN];
    const int t    = threadIdx.x;
    const int bid  = blockIdx.x;
    const int wgid = ((bid & 7) << 8) | (bid >> 3);
    const int b    = wgid >> 7;
    const int c0   = (wgid & 127) << 2;
    #pragma unroll
    for (int i = 0; i < 8; ++i) {
        const int l = t + (i << 8);
        const size_t base = (size_t)(b * LN + l) * HE + c0;
        const float4 qv = *(const float4*)(qg + base);
        const float4 kv = *(const float4*)(kg + base);
        const int sl = SIG(l);
        zb[0][sl] = make_float2(qv.x, kv.x);
        zb[1][sl] = make_float2(qv.y, kv.y);
        zb[2][sl] = make_float2(qv.z, kv.z);
        zb[3][sl] = make_float2(qv.w, kv.w);
    }
    __syncthreads();
    const int w    = t >> 6;
    const int lane = t & 63;
    float2* Z = zb[w];
    r8_stage<0>(Z, lane);
    r8_stage<3>(Z, lane);
    r8_stage<6>(Z, lane);
    r4_final(Z, lane);
    float sx[32], sy[32];
    #pragma unroll
    for (int i = 0; i < 32; ++i) {
        const int f = lane + (i << 6);
        const float2 zf = Z[SIG(f)];
        const float2 zm = Z[SIG((LN - f) & (LN - 1))];
        const float Qr = 0.5f * (zf.x + zm.x);
        const float Qi = 0.5f * (zf.y - zm.y);
        const float Kr = 0.5f * (zf.y + zm.y);
        const float Ki = -0.5f * (zf.x - zm.x);
        sx[i] = Qr * Kr + Qi * Ki;
        sy[i] = Qi * Kr - Qr * Ki;
    }
    __syncthreads();
    #pragma unroll
    for (int i = 0; i < 32; ++i) {
        const int f = lane + (i << 6);
        Z[SIG(f)] = make_float2(sx[i], sy[i]);
    }
    __syncthreads();
    #pragma unroll
    for (int i = 0; i < 8; ++i) {
        const int f  = t + (i << 8);
        const int sf = SIG(f);
        const float rx = zb[0][sf].x + zb[1][sf].x + zb[2][sf].x + zb[3][sf].x;
        const float ry = zb[0][sf].y + zb[1][sf].y + zb[2][sf].y + zb[3][sf].y;
        atomicAdd(&spec[((size_t)b * LN + f) * 2 + 0], rx);
        atomicAdd(&spec[((size_t)b * LN + f) * 2 + 1], ry);
    }
}

// ---------------------------------------------------------------------------
// Kernel B: per-b inverse transform -> mean corr, top-7 + softmax.
// ---------------------------------------------------------------------------
__device__ __forceinline__ unsigned bitrev11(unsigned x) {
    return __brev(x) >> (32 - LOG2L);
}

__global__ __launch_bounds__(256) void icorr_topk_kernel(
    const float* __restrict__ spec, float* __restrict__ wts, int* __restrict__ tao) {
    __shared__ float2 zbuf[LN];
    __shared__ float2 tw[LN / 2];
    __shared__ float  cr[LN];
    __shared__ float  rv[256];
    __shared__ int    ri[256];
    __shared__ float  topv[KTOP];
    __shared__ int    topi[KTOP];
    const int tid = threadIdx.x;
    const int b   = blockIdx.x;
    for (int p = tid; p < LN / 2; p += 256) {
        float s, c;
        sincosf(-TWO_PI * (float)p / (float)LN, &s, &c);
        tw[p] = make_float2(c, s);
    }
    for (int f = tid; f < LN; f += 256) {
        float sr = spec[((size_t)b * LN + f) * 2 + 0];
        float si = spec[((size_t)b * LN + f) * 2 + 1];
        zbuf[bitrev11((unsigned)f)] = make_float2(sr, -si);
    }
    __syncthreads();
    for (int s = 0; s < LOG2L; ++s) {
        const int half = 1 << s;
        for (int j = tid; j < LN / 2; j += 256) {
            const int grp = j >> s;
            const int pos = j & (half - 1);
            const int i0  = (grp << (s + 1)) + pos;
            const int i1  = i0 + half;
            const float2 w = tw[pos << (LOG2L - 1 - s)];
            float2 a  = zbuf[i0];
            float2 bv = zbuf[i1];
            float tr = w.x * bv.x - w.y * bv.y;
            float ti = w.x * bv.y + w.y * bv.x;
            zbuf[i0] = make_float2(a.x + tr, a.y + ti);
            zbuf[i1] = make_float2(a.x - tr, a.y - ti);
        }
        __syncthreads();
    }
    const float scale = 1.0f / ((float)LN * (float)HE);
    for (int t = tid; t < LN; t += 256) cr[t] = zbuf[t].x * scale;
    __syncthreads();
    for (int it = 0; it < KTOP; ++it) {
        float mv = -INFINITY;
        int   mi = 0;
        for (int t = tid; t < LN; t += 256) {
            float v = cr[t];
            if (v > mv) { mv = v; mi = t; }
        }
        rv[tid] = mv; ri[tid] = mi;
        __syncthreads();
        for (int off = 128; off > 0; off >>= 1) {
            if (tid < off) {
                float ov = rv[tid + off]; int oi = ri[tid + off];
                if (ov > rv[tid] || (ov == rv[tid] && oi < ri[tid])) {
                    rv[tid] = ov; ri[tid] = oi;
                }
            }
            __syncthreads();
        }
        if (tid == 0) {
            topv[it] = rv[0];
            topi[it] = ri[0];
            cr[ri[0]] = -INFINITY;
        }
        __syncthreads();
    }
    if (tid == 0) {
        float m = topv[0];
        float s = 0.f;
        float ex[KTOP];
        for (int j = 0; j < KTOP; ++j) { ex[j] = __expf(topv[j] - m); s += ex[j]; }
        float inv = 1.0f / s;
        for (int j = 0; j < KTOP; ++j) {
            wts[b * 8 + j] = ex[j] * inv;
            tao[b * 8 + j] = topi[j];
        }
    }
}

// ---------------------------------------------------------------------------
// Kernel C: out[b,l,:,:] = sum_j w[b,j] * V[b,(l+tao_j)%L,:,:]
// ---------------------------------------------------------------------------
__global__ __launch_bounds__(256) void gather_kernel(
    const float* __restrict__ v, const float* __restrict__ wts,
    const int* __restrict__ tao, float* __restrict__ out) {
    __shared__ float lw[KTOP];
    __shared__ int   lt[KTOP];
    const int tid = threadIdx.x;
    const int bid = blockIdx.x;
    const int wg  = ((bid & 7) << 11) | (bid >> 3);
    const long long idx = (long long)wg * 256 + tid;
    const int c4 = (int)(idx & 127);
    const int l  = (int)((idx >> 7) & (LN - 1));
    const int b  = (int)(idx >> 18);
    if (tid < KTOP) {
        lw[tid] = wts[b * 8 + tid];
        lt[tid] = tao[b * 8 + tid];
    }
    __syncthreads();
    const float4* v4 = (const float4*)v;
    float4 a = make_float4(0.f, 0.f, 0.f, 0.f);
    #pragma unroll
    for (int j = 0; j < KTOP; ++j) {
        int ls = (l + lt[j]) & (LN - 1);
        float4 x = v4[((size_t)b * LN + ls) * 128 + c4];
        float w = lw[j];
        a.x += w * x.x; a.y += w * x.y; a.z += w * x.z; a.w += w * x.w;
    }
    ((float4*)out)[idx] = a;
}

// ---------------------------------------------------------------------------
extern "C" void kernel_launch(void* const* d_in, const int* in_sizes, int n_in,
                              void* d_out, int out_size, void* d_ws, size_t ws_size,
                              hipStream_t stream) {
    const float* q = (const float*)d_in[0];
    const float* k = (const float*)d_in[1];
    const float* v = (const float*)d_in[2];
    float* out = (float*)d_out;

    const size_t nT   = (size_t)BB * HE * LN;          // 64 MB of floats
    const size_t need = nT * 4 + (size_t)BB * LN * 2 * 4 + (size_t)BB * 8 * 8;

    if (ws_size >= need) {
        float* kT   = (float*)d_ws;
        float* spec = kT + nT;
        float* wts  = spec + (size_t)BB * LN * 2;
        int*   tao  = (int*)(wts + BB * 8);
        float* qT   = out;   // staged in d_out, overwritten by gather later

        hipMemsetAsync(spec, 0, (size_t)BB * LN * 2 * sizeof(float), stream);
        transpose_pack_kernel<<<BB * 32 * 8, 256, 0, stream>>>(q, k, qT, kT);
        fft_wg_kernel<<<BB * (HE / 4), 256, 0, stream>>>(qT, kT, spec);
        icorr_topk_kernel<<<BB, 256, 0, stream>>>(spec, wts, tao);
        const int n4 = BB * LN * HE / 4;
        gather_kernel<<<n4 / 256, 256, 0, stream>>>(v, wts, tao, out);
    } else {
        float* spec = (float*)d_ws;
        float* wts  = spec + (size_t)BB * LN * 2;
        int*   tao  = (int*)(wts + BB * 8);
        hipMemsetAsync(spec, 0, (size_t)BB * LN * 2 * sizeof(float), stream);
        fft_fused_kernel<<<BB * (HE / 4), 256, 0, stream>>>(q, k, spec);
        icorr_topk_kernel<<<BB, 256, 0, stream>>>(spec, wts, tao);
        const int n4 = BB * LN * HE / 4;
        gather_kernel<<<n4 / 256, 256, 0, stream>>>(v, wts, tao, out);
    }
}